// Round 1
// baseline (179.444 us; speedup 1.0000x reference)
//
#include <hip/hip_runtime.h>

// Problem constants (fixed by harness shapes)
static constexpr int B2   = 2;
static constexpr int C    = 256;
static constexpr int H    = 48;
static constexpr int W    = 64;
static constexpr int NLVL = 4;
static constexpr int D1   = 32;
static constexpr int P    = H * W;  // 3072

// Workspace layout (floats):
//   f1cl : [B][H][W][C]   channels-last fmap1                 @ 0
//   pyr  : levels 0..3 channels-last fmap2 pyramid            @ F1SZ
static constexpr size_t F1SZ = (size_t)B2 * P * C;                 // 1,572,864
static constexpr size_t L0   = 0;
static constexpr size_t L1   = L0 + (size_t)B2 * 48 * 64 * C;      // 1,572,864
static constexpr size_t L2   = L1 + (size_t)B2 * 24 * 32 * C;      // 1,966,080
static constexpr size_t L3   = L2 + (size_t)B2 * 12 * 16 * C;      // 2,064,384
static constexpr size_t PYRSZ = L3 + (size_t)B2 * 6 * 8 * C;       // 2,088,960

// ---------------------------------------------------------------------------
// Kernel A: transpose fmap1 and fmap2 from [B,C,H,W] to channels-last
// [B,H,W,C]. fmap1 -> ws[0..F1SZ), fmap2 -> ws[F1SZ..F1SZ+level0).
// Standard 32x32 LDS tile transpose, coalesced on both sides.
// grid (P/32=96, C/32=8, 4 images), block (32,8)
// ---------------------------------------------------------------------------
__global__ __launch_bounds__(256) void k_transpose_cl(
    const float* __restrict__ f1, const float* __restrict__ f2,
    float* __restrict__ ws) {
  __shared__ float tile[32][33];
  const int img = blockIdx.z;  // 0,1 = fmap1 b; 2,3 = fmap2 b
  const int b = img & 1;
  const float* src = ((img < 2) ? f1 : f2) + (size_t)b * C * P;
  float* dst = ws + ((img < 2) ? (size_t)0 : F1SZ) + (size_t)b * P * C;
  const int p0 = blockIdx.x * 32;
  const int c0 = blockIdx.y * 32;
  const int tx = threadIdx.x, ty = threadIdx.y;
#pragma unroll
  for (int i = 0; i < 32; i += 8)
    tile[ty + i][tx] = src[(size_t)(c0 + ty + i) * P + (p0 + tx)];
  __syncthreads();
#pragma unroll
  for (int i = 0; i < 32; i += 8)
    dst[(size_t)(p0 + ty + i) * C + (c0 + tx)] = tile[tx][ty + i];
}

// ---------------------------------------------------------------------------
// Kernel B: build pyramid levels 1..3 directly from channels-last level 0.
// Level l pixel = mean over 2^l x 2^l block of level 0 (exact equivalent of
// chained 2x2 avg-pool). One block (256 thr = channels) per output pixel.
// grid = 2*768 + 2*192 + 2*48 = 2016 blocks
// ---------------------------------------------------------------------------
__global__ __launch_bounds__(256) void k_pyramid(float* __restrict__ ws) {
  const float* lvl0 = ws + F1SZ + L0;
  const int id = blockIdx.x;
  int lvl, rem;
  if (id < 1536)      { lvl = 1; rem = id; }
  else if (id < 1920) { lvl = 2; rem = id - 1536; }
  else                { lvl = 3; rem = id - 1920; }
  const int Hi = H >> lvl, Wi = W >> lvl;
  const int b  = rem / (Hi * Wi);
  const int pp = rem - b * (Hi * Wi);
  const int yy = pp / Wi, xx = pp - (pp / Wi) * Wi;
  const int k  = 1 << lvl;
  const int t  = threadIdx.x;
  const float* src = lvl0 + (size_t)b * P * C;
  float acc = 0.f;
  for (int dy = 0; dy < k; ++dy)
    for (int dx = 0; dx < k; ++dx)
      acc += src[((size_t)(yy * k + dy) * W + (xx * k + dx)) * C + t];
  const size_t loff = (lvl == 1) ? L1 : (lvl == 2) ? L2 : L3;
  ws[F1SZ + loff + (((size_t)b * Hi + yy) * Wi + xx) * C + t] =
      acc * (1.f / (float)(k * k));
}

// ---------------------------------------------------------------------------
// Kernel C: main sampler. One block per (b,y,x). 256 threads = 4 waves.
// Lane owns channels [4*lane, 4*lane+4). Each wave handles d-slice
// [8*wave, 8*wave+8) for every level. Coords staged in LDS once per block.
// Corner gathers: 64-lane float4 loads, fully coalesced (channels-last).
// Head reduction: shfl_xor over 8-lane groups (32 channels/head).
// ---------------------------------------------------------------------------
__global__ __launch_bounds__(256) void k_sample(
    const float* __restrict__ ws, const float* __restrict__ coords,
    float* __restrict__ out) {
  __shared__ float lc[2][NLVL][D1];
  const int bid = blockIdx.x;
  const int b   = bid / P;
  const int pix = bid - b * P;
  const int y   = pix >> 6;   // /W (W=64)
  const int x   = pix & 63;
  const int t   = threadIdx.x;

  // stage coords[b, j, lvl, d, y, x] for all (j,lvl,d) — 256 values
  {
    const int j = t >> 7, r = t & 127, lv = r >> 5, d = r & 31;
    lc[j][lv][d] =
        coords[((((size_t)(b * 2 + j) * NLVL + lv) * D1 + d) * H + y) * W + x];
  }

  const int lane = t & 63;
  const int wave = t >> 6;
  const int head = lane >> 3;  // channel group 32*head .. +31
  const float4 f1v = *reinterpret_cast<const float4*>(
      ws + (((size_t)b * H + y) * W + x) * C + lane * 4);
  __syncthreads();

  const float* pyr = ws + F1SZ;
#pragma unroll
  for (int lvl = 0; lvl < NLVL; ++lvl) {
    const int Hi = H >> lvl, Wi = W >> lvl;
    const size_t loff = (lvl == 0) ? L0 : (lvl == 1) ? L1 : (lvl == 2) ? L2 : L3;
    const float* img = pyr + loff + (size_t)b * Hi * Wi * C;
    const float sc = 1.0f / (float)(1 << lvl);
#pragma unroll
    for (int dd = 0; dd < 8; ++dd) {
      const int d = wave * 8 + dd;
      const float cx = lc[0][lvl][d];
      const float cy = lc[1][lvl][d];
      const float xf = (cx + 0.5f) * sc - 0.5f;
      const float yf = (cy + 0.5f) * sc - 0.5f;
      const float x0f = floorf(xf), y0f = floorf(yf);
      const int x0 = (int)x0f, y0 = (int)y0f;
      const float fx = xf - x0f, fy = yf - y0f;
      const float w00 = (1.f - fx) * (1.f - fy);
      const float w10 = fx * (1.f - fy);
      const float w01 = (1.f - fx) * fy;
      const float w11 = fx * fy;

      float sx = 0.f, sy = 0.f, sz = 0.f, sw = 0.f;
      const bool vx0 = (x0 >= 0) && (x0 < Wi);
      const bool vx1 = (x0 + 1 >= 0) && (x0 + 1 < Wi);
      const bool vy0 = (y0 >= 0) && (y0 < Hi);
      const bool vy1 = (y0 + 1 >= 0) && (y0 + 1 < Hi);
      // validity is wave-uniform (coords uniform per point): no divergence
      if (vy0) {
        const float* row = img + (size_t)y0 * Wi * C + lane * 4;
        if (vx0) {
          const float4 v = *reinterpret_cast<const float4*>(row + (size_t)x0 * C);
          sx += w00 * v.x; sy += w00 * v.y; sz += w00 * v.z; sw += w00 * v.w;
        }
        if (vx1) {
          const float4 v = *reinterpret_cast<const float4*>(row + (size_t)(x0 + 1) * C);
          sx += w10 * v.x; sy += w10 * v.y; sz += w10 * v.z; sw += w10 * v.w;
        }
      }
      if (vy1) {
        const float* row = img + (size_t)(y0 + 1) * Wi * C + lane * 4;
        if (vx0) {
          const float4 v = *reinterpret_cast<const float4*>(row + (size_t)x0 * C);
          sx += w01 * v.x; sy += w01 * v.y; sz += w01 * v.z; sw += w01 * v.w;
        }
        if (vx1) {
          const float4 v = *reinterpret_cast<const float4*>(row + (size_t)(x0 + 1) * C);
          sx += w11 * v.x; sy += w11 * v.y; sz += w11 * v.z; sw += w11 * v.w;
        }
      }

      float a = fabsf(f1v.x - sx) + fabsf(f1v.y - sy) +
                fabsf(f1v.z - sz) + fabsf(f1v.w - sw);
      a += __shfl_xor(a, 1);
      a += __shfl_xor(a, 2);
      a += __shfl_xor(a, 4);
      if ((lane & 7) == 0)
        out[(((size_t)b * (NLVL * 256) + lvl * 256 + head * 32 + d) * H + y) * W + x] =
            a * (1.0f / 32.0f);
    }
  }
}

extern "C" void kernel_launch(void* const* d_in, const int* in_sizes, int n_in,
                              void* d_out, int out_size, void* d_ws, size_t ws_size,
                              hipStream_t stream) {
  const float* fmap1  = (const float*)d_in[0];
  const float* fmap2  = (const float*)d_in[1];
  const float* coords = (const float*)d_in[2];
  float* out = (float*)d_out;
  float* ws  = (float*)d_ws;  // needs (F1SZ + PYRSZ)*4 = ~14.6 MB

  dim3 gA(P / 32, C / 32, 4), bA(32, 8);
  k_transpose_cl<<<gA, bA, 0, stream>>>(fmap1, fmap2, ws);
  k_pyramid<<<2016, 256, 0, stream>>>(ws);
  k_sample<<<B2 * P, 256, 0, stream>>>(ws, coords, out);
}

// Round 2
// 105.167 us; speedup vs baseline: 1.7063x; 1.7063x over previous
//
#include <hip/hip_runtime.h>

// Problem constants (fixed by harness shapes)
static constexpr int B2   = 2;
static constexpr int C    = 256;
static constexpr int H    = 48;
static constexpr int W    = 64;
static constexpr int NLVL = 4;
static constexpr int D1   = 32;
static constexpr int P    = H * W;   // 3072
static constexpr int CHO  = NLVL * 8 * D1;  // 1024 output channels

// Workspace layout:
//   bf16 f1cl : [B][P][C]                  elems [0, F1E)
//   bf16 pyr  : levels 0..3 channels-last  elems [F1E, F1E+PYRE)
//   f32  out_tmp : [B][P][CHO]             bytes [OT_OFF, OT_OFF + OT_BYTES)
static constexpr size_t F1E  = (size_t)B2 * P * C;              // 1,572,864
static constexpr size_t L0E  = 0;
static constexpr size_t L1E  = L0E + (size_t)B2 * 48 * 64 * C;  // 1,572,864
static constexpr size_t L2E  = L1E + (size_t)B2 * 24 * 32 * C;
static constexpr size_t L3E  = L2E + (size_t)B2 * 12 * 16 * C;
static constexpr size_t PYRE = L3E + (size_t)B2 * 6 * 8 * C;    // 2,088,960
static constexpr size_t OT_OFF   = 2 * (F1E + PYRE);            // bytes, 16B-aligned
static constexpr size_t OT_BYTES = (size_t)B2 * P * CHO * 4;
static constexpr size_t WS_NEEDED = OT_OFF + OT_BYTES;          // ~32.5 MB

__device__ __forceinline__ float bflo(unsigned u) { return __uint_as_float(u << 16); }
__device__ __forceinline__ float bfhi(unsigned u) { return __uint_as_float(u & 0xffff0000u); }
__device__ __forceinline__ unsigned short f2bf(float f) {
  unsigned u = __float_as_uint(f);
  return (unsigned short)((u + 0x7fffu + ((u >> 16) & 1u)) >> 16);
}

// ---------------------------------------------------------------------------
// A: [B,C,H,W] f32 -> channels-last [B,P,C] bf16 for fmap1 and fmap2.
// grid (96, 8, 4), block (32,8)
// ---------------------------------------------------------------------------
__global__ __launch_bounds__(256) void k_transpose_cl(
    const float* __restrict__ f1, const float* __restrict__ f2,
    unsigned short* __restrict__ ws) {
  __shared__ float tile[32][33];
  const int img = blockIdx.z;  // 0,1 = fmap1 b; 2,3 = fmap2 b
  const int b = img & 1;
  const float* src = ((img < 2) ? f1 : f2) + (size_t)b * C * P;
  unsigned short* dst = ws + ((img < 2) ? (size_t)0 : F1E) + (size_t)b * P * C;
  const int p0 = blockIdx.x * 32;
  const int c0 = blockIdx.y * 32;
  const int tx = threadIdx.x, ty = threadIdx.y;
#pragma unroll
  for (int i = 0; i < 32; i += 8)
    tile[ty + i][tx] = src[(size_t)(c0 + ty + i) * P + (p0 + tx)];
  __syncthreads();
#pragma unroll
  for (int i = 0; i < 32; i += 8)
    dst[(size_t)(p0 + ty + i) * C + (c0 + tx)] = f2bf(tile[tx][ty + i]);
}

// ---------------------------------------------------------------------------
// B: build pyramid levels 1..3 from channels-last bf16 level 0 (exact mean
// over 2^l x 2^l block, f32 accumulate). One block (256 thr = channels) per
// output pixel. grid = 2016
// ---------------------------------------------------------------------------
__global__ __launch_bounds__(256) void k_pyramid(unsigned short* __restrict__ ws) {
  const unsigned short* lvl0 = ws + F1E;
  const int id = blockIdx.x;
  int lvl, rem;
  if (id < 1536)      { lvl = 1; rem = id; }
  else if (id < 1920) { lvl = 2; rem = id - 1536; }
  else                { lvl = 3; rem = id - 1920; }
  const int Hi = H >> lvl, Wi = W >> lvl;
  const int b  = rem / (Hi * Wi);
  const int pp = rem - b * (Hi * Wi);
  const int yy = pp / Wi, xx = pp - (pp / Wi) * Wi;
  const int k  = 1 << lvl;
  const int t  = threadIdx.x;
  const unsigned short* src = lvl0 + (size_t)b * P * C;
  float acc = 0.f;
  for (int dy = 0; dy < k; ++dy)
    for (int dx = 0; dx < k; ++dx)
      acc += bflo((unsigned)src[((size_t)(yy * k + dy) * W + (xx * k + dx)) * C + t]);
  const size_t loff = (lvl == 1) ? L1E : (lvl == 2) ? L2E : L3E;
  ws[F1E + loff + (((size_t)b * Hi + yy) * Wi + xx) * C + t] =
      f2bf(acc * (1.f / (float)(k * k)));
}

// ---------------------------------------------------------------------------
// C: main sampler. One block per (b,pix). 256 threads = 4 waves.
// Phase 0: 128 threads precompute (per lvl,d): 4 corner element-offsets
//          (clamped) + 4 weights (premultiplied by validity) into LDS.
// Main:    wave w handles d in [8w,8w+8); lanes 0-31 / 32-63 take the two d
//          of each pair. Lane owns 8 bf16 channels (uint4 = 16B load).
//          Per corner: 1 coalesced 512B gather per half-wave.
// Reduce:  8-ch in-lane sum of |f1-s|, then shfl_xor over 4-lane head group.
// STAGED=1: results staged in LDS, written as one contiguous 4KB block to
//          out_tmp[b][pix][ch]. STAGED=0: direct strided 4B writes.
// ---------------------------------------------------------------------------
template <int STAGED>
__global__ __launch_bounds__(256) void k_sample(
    const unsigned short* __restrict__ wsb, const float* __restrict__ coords,
    float* __restrict__ dst) {
  __shared__ uint4  s_off[128];
  __shared__ float4 s_w[128];
  __shared__ float  s_out[CHO];
  const int bid = blockIdx.x;
  const int b   = (bid >= P) ? 1 : 0;
  const int pix = bid - b * P;
  const int t   = threadIdx.x;

  if (t < 128) {
    const int lvl = t >> 5, d = t & 31;
    const float cx = coords[(((size_t)(b * 2 + 0) * NLVL + lvl) * D1 + d) * P + pix];
    const float cy = coords[(((size_t)(b * 2 + 1) * NLVL + lvl) * D1 + d) * P + pix];
    const int Hi = H >> lvl, Wi = W >> lvl;
    const float sc = 1.0f / (float)(1 << lvl);
    const float xf = (cx + 0.5f) * sc - 0.5f;
    const float yf = (cy + 0.5f) * sc - 0.5f;
    const float x0f = floorf(xf), y0f = floorf(yf);
    const int x0 = (int)x0f, y0 = (int)y0f;
    const int x1 = x0 + 1, y1 = y0 + 1;
    const float fx = xf - x0f, fy = yf - y0f;
    const float vx0 = (x0 >= 0 && x0 < Wi) ? 1.f : 0.f;
    const float vx1 = (x1 >= 0 && x1 < Wi) ? 1.f : 0.f;
    const float vy0 = (y0 >= 0 && y0 < Hi) ? 1.f : 0.f;
    const float vy1 = (y1 >= 0 && y1 < Hi) ? 1.f : 0.f;
    const int x0c = min(max(x0, 0), Wi - 1), x1c = min(max(x1, 0), Wi - 1);
    const int y0c = min(max(y0, 0), Hi - 1), y1c = min(max(y1, 0), Hi - 1);
    s_w[t] = make_float4((1.f - fx) * (1.f - fy) * vx0 * vy0,
                         fx * (1.f - fy) * vx1 * vy0,
                         (1.f - fx) * fy * vx0 * vy1,
                         fx * fy * vx1 * vy1);
    s_off[t] = make_uint4((unsigned)(y0c * Wi + x0c) * C,
                          (unsigned)(y0c * Wi + x1c) * C,
                          (unsigned)(y1c * Wi + x0c) * C,
                          (unsigned)(y1c * Wi + x1c) * C);
  }

  const int lane = t & 63;
  const int wave = t >> 6;
  const int half = lane >> 5;
  const int ch0  = (lane & 31) * 8;
  const int head = (lane & 31) >> 2;

  // f1 fragment: 8 channels as f32
  float f1r[8];
  {
    const uint4 v = *reinterpret_cast<const uint4*>(
        wsb + ((size_t)b * P + pix) * C + ch0);
    f1r[0] = bflo(v.x); f1r[1] = bfhi(v.x);
    f1r[2] = bflo(v.y); f1r[3] = bfhi(v.y);
    f1r[4] = bflo(v.z); f1r[5] = bfhi(v.z);
    f1r[6] = bflo(v.w); f1r[7] = bfhi(v.w);
  }

  const unsigned short* pyr = wsb + F1E;
  const unsigned short* imgs[NLVL] = {
      pyr + L0E + (size_t)b * 48 * 64 * C, pyr + L1E + (size_t)b * 24 * 32 * C,
      pyr + L2E + (size_t)b * 12 * 16 * C, pyr + L3E + (size_t)b * 6 * 8 * C};

  __syncthreads();

#pragma unroll
  for (int lvl = 0; lvl < NLVL; ++lvl) {
    const unsigned short* img = imgs[lvl];
#pragma unroll
    for (int i = 0; i < 4; ++i) {
      const int d   = wave * 8 + i * 2 + half;
      const int idx = lvl * 32 + d;
      const uint4  offs = s_off[idx];
      const float4 wv   = s_w[idx];
      float acc[8] = {0.f, 0.f, 0.f, 0.f, 0.f, 0.f, 0.f, 0.f};
      {
        const uint4 v = *reinterpret_cast<const uint4*>(img + offs.x + ch0);
        acc[0] += wv.x * bflo(v.x); acc[1] += wv.x * bfhi(v.x);
        acc[2] += wv.x * bflo(v.y); acc[3] += wv.x * bfhi(v.y);
        acc[4] += wv.x * bflo(v.z); acc[5] += wv.x * bfhi(v.z);
        acc[6] += wv.x * bflo(v.w); acc[7] += wv.x * bfhi(v.w);
      }
      {
        const uint4 v = *reinterpret_cast<const uint4*>(img + offs.y + ch0);
        acc[0] += wv.y * bflo(v.x); acc[1] += wv.y * bfhi(v.x);
        acc[2] += wv.y * bflo(v.y); acc[3] += wv.y * bfhi(v.y);
        acc[4] += wv.y * bflo(v.z); acc[5] += wv.y * bfhi(v.z);
        acc[6] += wv.y * bflo(v.w); acc[7] += wv.y * bfhi(v.w);
      }
      {
        const uint4 v = *reinterpret_cast<const uint4*>(img + offs.z + ch0);
        acc[0] += wv.z * bflo(v.x); acc[1] += wv.z * bfhi(v.x);
        acc[2] += wv.z * bflo(v.y); acc[3] += wv.z * bfhi(v.y);
        acc[4] += wv.z * bflo(v.z); acc[5] += wv.z * bfhi(v.z);
        acc[6] += wv.z * bflo(v.w); acc[7] += wv.z * bfhi(v.w);
      }
      {
        const uint4 v = *reinterpret_cast<const uint4*>(img + offs.w + ch0);
        acc[0] += wv.w * bflo(v.x); acc[1] += wv.w * bfhi(v.x);
        acc[2] += wv.w * bflo(v.y); acc[3] += wv.w * bfhi(v.y);
        acc[4] += wv.w * bflo(v.z); acc[5] += wv.w * bfhi(v.z);
        acc[6] += wv.w * bflo(v.w); acc[7] += wv.w * bfhi(v.w);
      }
      float a = 0.f;
#pragma unroll
      for (int k = 0; k < 8; ++k) a += fabsf(f1r[k] - acc[k]);
      a += __shfl_xor(a, 1);
      a += __shfl_xor(a, 2);
      if ((lane & 3) == 0) {
        const int ch_out = lvl * 256 + head * 32 + d;
        if (STAGED)
          s_out[ch_out] = a * (1.0f / 32.0f);
        else
          dst[((size_t)b * CHO + ch_out) * P + pix] = a * (1.0f / 32.0f);
      }
    }
  }

  if (STAGED) {
    __syncthreads();
    *reinterpret_cast<float4*>(dst + ((size_t)b * P + pix) * CHO + t * 4) =
        *reinterpret_cast<const float4*>(&s_out[t * 4]);
  }
}

// ---------------------------------------------------------------------------
// D: transpose out_tmp [B][P][CHO] -> out [B][CHO][P], coalesced both sides.
// grid (96, 32, 2), block (32,8)
// ---------------------------------------------------------------------------
__global__ __launch_bounds__(256) void k_out_t(
    const float* __restrict__ ot, float* __restrict__ out) {
  __shared__ float tile[32][33];
  const int b  = blockIdx.z;
  const int p0 = blockIdx.x * 32;
  const int c0 = blockIdx.y * 32;
  const int tx = threadIdx.x, ty = threadIdx.y;
#pragma unroll
  for (int i = 0; i < 32; i += 8)
    tile[ty + i][tx] = ot[((size_t)b * P + p0 + ty + i) * CHO + c0 + tx];
  __syncthreads();
#pragma unroll
  for (int i = 0; i < 32; i += 8)
    out[((size_t)b * CHO + c0 + ty + i) * P + p0 + tx] = tile[tx][ty + i];
}

extern "C" void kernel_launch(void* const* d_in, const int* in_sizes, int n_in,
                              void* d_out, int out_size, void* d_ws, size_t ws_size,
                              hipStream_t stream) {
  const float* fmap1  = (const float*)d_in[0];
  const float* fmap2  = (const float*)d_in[1];
  const float* coords = (const float*)d_in[2];
  float* out = (float*)d_out;
  unsigned short* wsb = (unsigned short*)d_ws;

  dim3 gA(P / 32, C / 32, 4), bA(32, 8);
  k_transpose_cl<<<gA, bA, 0, stream>>>(fmap1, fmap2, wsb);
  k_pyramid<<<2016, 256, 0, stream>>>(wsb);

  if (ws_size >= WS_NEEDED) {
    float* ot = (float*)((char*)d_ws + OT_OFF);
    k_sample<1><<<B2 * P, 256, 0, stream>>>(wsb, coords, ot);
    k_out_t<<<dim3(96, 32, 2), dim3(32, 8), 0, stream>>>(ot, out);
  } else {
    k_sample<0><<<B2 * P, 256, 0, stream>>>(wsb, coords, out);
  }
}

// Round 3
// 96.415 us; speedup vs baseline: 1.8612x; 1.0908x over previous
//
#include <hip/hip_runtime.h>

typedef _Float16 h2 __attribute__((ext_vector_type(2)));

// Problem constants (fixed by harness shapes)
static constexpr int B2   = 2;
static constexpr int C    = 256;
static constexpr int H    = 48;
static constexpr int W    = 64;
static constexpr int NLVL = 4;
static constexpr int D1   = 32;
static constexpr int P    = H * W;          // 3072
static constexpr int CHO  = NLVL * 8 * D1;  // 1024 output channels

// Workspace layout:
//   fp16 f1cl : [B][P][C]                  elems [0, F1E)
//   fp16 pyr  : levels 0..3 channels-last  elems [F1E, F1E+PYRE)
//   f32  out_tmp : [B][P][CHO]             bytes [OT_OFF, ...)
static constexpr size_t F1E  = (size_t)B2 * P * C;
static constexpr size_t L0E  = 0;
static constexpr size_t L1E  = L0E + (size_t)B2 * 48 * 64 * C;
static constexpr size_t L2E  = L1E + (size_t)B2 * 24 * 32 * C;
static constexpr size_t L3E  = L2E + (size_t)B2 * 12 * 16 * C;
static constexpr size_t PYRE = L3E + (size_t)B2 * 6 * 8 * C;
static constexpr size_t OT_OFF    = 2 * (F1E + PYRE);  // bytes, 16B-aligned
static constexpr size_t OT_BYTES  = (size_t)B2 * P * CHO * 4;
static constexpr size_t WS_NEEDED = OT_OFF + OT_BYTES; // ~32.5 MB

__device__ __forceinline__ h2 u2h(unsigned u) {
  union { unsigned u; h2 h; } c; c.u = u; return c.h;
}
__device__ __forceinline__ unsigned h2u(h2 h) {
  union { unsigned u; h2 h; } c; c.h = h; return c.u;
}
__device__ __forceinline__ h2 habs2(h2 x) { return u2h(h2u(x) & 0x7FFF7FFFu); }

// ---------------------------------------------------------------------------
// A: [B,C,H,W] f32 -> channels-last [B,P,C] fp16 for fmap1 and fmap2.
// grid (96, 8, 4), block (32,8)
// ---------------------------------------------------------------------------
__global__ __launch_bounds__(256) void k_transpose_cl(
    const float* __restrict__ f1, const float* __restrict__ f2,
    _Float16* __restrict__ ws) {
  __shared__ float tile[32][33];
  const int img = blockIdx.z;  // 0,1 = fmap1 b; 2,3 = fmap2 b
  const int b = img & 1;
  const float* src = ((img < 2) ? f1 : f2) + (size_t)b * C * P;
  _Float16* dst = ws + ((img < 2) ? (size_t)0 : F1E) + (size_t)b * P * C;
  const int p0 = blockIdx.x * 32;
  const int c0 = blockIdx.y * 32;
  const int tx = threadIdx.x, ty = threadIdx.y;
#pragma unroll
  for (int i = 0; i < 32; i += 8)
    tile[ty + i][tx] = src[(size_t)(c0 + ty + i) * P + (p0 + tx)];
  __syncthreads();
#pragma unroll
  for (int i = 0; i < 32; i += 8)
    dst[(size_t)(p0 + ty + i) * C + (c0 + tx)] = (_Float16)tile[tx][ty + i];
}

// ---------------------------------------------------------------------------
// B: build pyramid levels 1..3 from channels-last fp16 level 0 (exact mean
// over 2^l x 2^l block, f32 accumulate). One block (256 thr = channels) per
// output pixel. grid = 2016
// ---------------------------------------------------------------------------
__global__ __launch_bounds__(256) void k_pyramid(_Float16* __restrict__ ws) {
  const _Float16* lvl0 = ws + F1E;
  const int id = blockIdx.x;
  int lvl, rem;
  if (id < 1536)      { lvl = 1; rem = id; }
  else if (id < 1920) { lvl = 2; rem = id - 1536; }
  else                { lvl = 3; rem = id - 1920; }
  const int Hi = H >> lvl, Wi = W >> lvl;
  const int b  = rem / (Hi * Wi);
  const int pp = rem - b * (Hi * Wi);
  const int yy = pp / Wi, xx = pp - (pp / Wi) * Wi;
  const int k  = 1 << lvl;
  const int t  = threadIdx.x;
  const _Float16* src = lvl0 + (size_t)b * P * C;
  float acc = 0.f;
  for (int dy = 0; dy < k; ++dy)
    for (int dx = 0; dx < k; ++dx)
      acc += (float)src[((size_t)(yy * k + dy) * W + (xx * k + dx)) * C + t];
  const size_t loff = (lvl == 1) ? L1E : (lvl == 2) ? L2E : L3E;
  ws[F1E + loff + (((size_t)b * Hi + yy) * Wi + xx) * C + t] =
      (_Float16)(acc * (1.f / (float)(k * k)));
}

// ---------------------------------------------------------------------------
// C: main sampler. One block per (b,pix), XCD-chunk-swizzled. 256 thr = 4 wv.
// Phase 0: 128 threads precompute per (lvl,d): 4 clamped corner BYTE offsets
//          + 4 validity-masked weights as packed fp16x2, into LDS.
// Main:    wave w, half h handles d = 8w+2i+h; lane owns 8 fp16 channels
//          (one uint4 = 16B coalesced gather per corner). Interp via
//          v_pk_fma_f16 (4/corner). |f1-s| summed with packed abs/add tree.
// Reduce:  f32 shfl_xor over 4-lane head group -> s_out (conflict-free
//          [d][33] layout), then one contiguous 4KB f32 block to out_tmp.
// ---------------------------------------------------------------------------
template <int STAGED>
__global__ __launch_bounds__(256) void k_sample(
    const _Float16* __restrict__ wsh, const float* __restrict__ coords,
    float* __restrict__ dst) {
  __shared__ uint4 s_off[128];
  __shared__ uint4 s_w[128];
  __shared__ float s_out[32 * 33];
  const int bid0 = blockIdx.x;
  const int bid  = (bid0 & 7) * 768 + (bid0 >> 3);  // XCD chunk swizzle (6144=8*768)
  const int b    = (bid >= P) ? 1 : 0;
  const int pix  = bid - b * P;
  const int t    = threadIdx.x;

  if (t < 128) {
    const int lvl = t >> 5, d = t & 31;
    const float cx = coords[(((size_t)(b * 2 + 0) * NLVL + lvl) * D1 + d) * P + pix];
    const float cy = coords[(((size_t)(b * 2 + 1) * NLVL + lvl) * D1 + d) * P + pix];
    const int Hi = H >> lvl, Wi = W >> lvl;
    const float sc = 1.0f / (float)(1 << lvl);
    const float xf = (cx + 0.5f) * sc - 0.5f;
    const float yf = (cy + 0.5f) * sc - 0.5f;
    const float x0f = floorf(xf), y0f = floorf(yf);
    const int x0 = (int)x0f, y0 = (int)y0f;
    const int x1 = x0 + 1, y1 = y0 + 1;
    const float fx = xf - x0f, fy = yf - y0f;
    const float vx0 = (x0 >= 0 && x0 < Wi) ? 1.f : 0.f;
    const float vx1 = (x1 >= 0 && x1 < Wi) ? 1.f : 0.f;
    const float vy0 = (y0 >= 0 && y0 < Hi) ? 1.f : 0.f;
    const float vy1 = (y1 >= 0 && y1 < Hi) ? 1.f : 0.f;
    const int x0c = min(max(x0, 0), Wi - 1), x1c = min(max(x1, 0), Wi - 1);
    const int y0c = min(max(y0, 0), Hi - 1), y1c = min(max(y1, 0), Hi - 1);
    h2 p00, p10, p01, p11;
    p00.x = p00.y = (_Float16)((1.f - fx) * (1.f - fy) * vx0 * vy0);
    p10.x = p10.y = (_Float16)(fx * (1.f - fy) * vx1 * vy0);
    p01.x = p01.y = (_Float16)((1.f - fx) * fy * vx0 * vy1);
    p11.x = p11.y = (_Float16)(fx * fy * vx1 * vy1);
    s_w[t] = make_uint4(h2u(p00), h2u(p10), h2u(p01), h2u(p11));
    // byte offsets within level image (fp16 elems, C*2 = 512 B per pixel)
    s_off[t] = make_uint4((unsigned)(y0c * Wi + x0c) * (C * 2),
                          (unsigned)(y0c * Wi + x1c) * (C * 2),
                          (unsigned)(y1c * Wi + x0c) * (C * 2),
                          (unsigned)(y1c * Wi + x1c) * (C * 2));
  }

  const int lane = t & 63;
  const int wave = t >> 6;
  const int half = lane >> 5;
  const int lsub = lane & 31;
  const int head = lsub >> 2;
  const int chb  = lsub * 16;  // byte offset of this lane's 8 fp16 channels

  // f1 fragment: 8 channels, kept packed fp16x2
  h2 f1h[4];
  {
    const uint4 v = *reinterpret_cast<const uint4*>(
        reinterpret_cast<const char*>(wsh + ((size_t)b * P + pix) * C) + chb);
    f1h[0] = u2h(v.x); f1h[1] = u2h(v.y); f1h[2] = u2h(v.z); f1h[3] = u2h(v.w);
  }
  const char* imgs[NLVL] = {
      reinterpret_cast<const char*>(wsh + F1E + L0E + (size_t)b * 48 * 64 * C),
      reinterpret_cast<const char*>(wsh + F1E + L1E + (size_t)b * 24 * 32 * C),
      reinterpret_cast<const char*>(wsh + F1E + L2E + (size_t)b * 12 * 16 * C),
      reinterpret_cast<const char*>(wsh + F1E + L3E + (size_t)b * 6 * 8 * C)};

  __syncthreads();

#pragma unroll
  for (int lvl = 0; lvl < NLVL; ++lvl) {
    const char* img = imgs[lvl];
#pragma unroll
    for (int i = 0; i < 4; ++i) {
      const int d   = wave * 8 + i * 2 + half;
      const int idx = lvl * 32 + d;
      const uint4 offs = s_off[idx];
      const uint4 wq   = s_w[idx];
      h2 a0 = {0, 0}, a1 = {0, 0}, a2 = {0, 0}, a3 = {0, 0};
      {
        const uint4 v = *reinterpret_cast<const uint4*>(img + offs.x + chb);
        const h2 w = u2h(wq.x);
        a0 += w * u2h(v.x); a1 += w * u2h(v.y); a2 += w * u2h(v.z); a3 += w * u2h(v.w);
      }
      {
        const uint4 v = *reinterpret_cast<const uint4*>(img + offs.y + chb);
        const h2 w = u2h(wq.y);
        a0 += w * u2h(v.x); a1 += w * u2h(v.y); a2 += w * u2h(v.z); a3 += w * u2h(v.w);
      }
      {
        const uint4 v = *reinterpret_cast<const uint4*>(img + offs.z + chb);
        const h2 w = u2h(wq.z);
        a0 += w * u2h(v.x); a1 += w * u2h(v.y); a2 += w * u2h(v.z); a3 += w * u2h(v.w);
      }
      {
        const uint4 v = *reinterpret_cast<const uint4*>(img + offs.w + chb);
        const h2 w = u2h(wq.w);
        a0 += w * u2h(v.x); a1 += w * u2h(v.y); a2 += w * u2h(v.z); a3 += w * u2h(v.w);
      }
      const h2 d0 = habs2(f1h[0] - a0);
      const h2 d1 = habs2(f1h[1] - a1);
      const h2 d2 = habs2(f1h[2] - a2);
      const h2 d3 = habs2(f1h[3] - a3);
      const h2 s  = (d0 + d1) + (d2 + d3);
      float a = (float)s.x + (float)s.y;
      a += __shfl_xor(a, 1);
      a += __shfl_xor(a, 2);
      if ((lane & 3) == 0) {
        if (STAGED) {
          // conflict-free: concurrent heads hit consecutive banks
          s_out[d * 33 + lvl * 8 + head] = a * (1.0f / 32.0f);
        } else {
          const int ch_out = lvl * 256 + head * 32 + d;
          dst[((size_t)b * CHO + ch_out) * P + pix] = a * (1.0f / 32.0f);
        }
      }
    }
  }

  if (STAGED) {
    __syncthreads();
    float rr[4];
#pragma unroll
    for (int j = 0; j < 4; ++j) {
      const int ch = t * 4 + j;
      rr[j] = s_out[(ch & 31) * 33 + (ch >> 8) * 8 + ((ch >> 5) & 7)];
    }
    *reinterpret_cast<float4*>(dst + ((size_t)b * P + pix) * CHO + t * 4) =
        make_float4(rr[0], rr[1], rr[2], rr[3]);
  }
}

// ---------------------------------------------------------------------------
// D: transpose out_tmp [B][P][CHO] -> out [B][CHO][P], coalesced both sides.
// grid (96, 32, 2), block (32,8)
// ---------------------------------------------------------------------------
__global__ __launch_bounds__(256) void k_out_t(
    const float* __restrict__ ot, float* __restrict__ out) {
  __shared__ float tile[32][33];
  const int b  = blockIdx.z;
  const int p0 = blockIdx.x * 32;
  const int c0 = blockIdx.y * 32;
  const int tx = threadIdx.x, ty = threadIdx.y;
#pragma unroll
  for (int i = 0; i < 32; i += 8)
    tile[ty + i][tx] = ot[((size_t)b * P + p0 + ty + i) * CHO + c0 + tx];
  __syncthreads();
#pragma unroll
  for (int i = 0; i < 32; i += 8)
    out[((size_t)b * CHO + c0 + ty + i) * P + p0 + tx] = tile[tx][ty + i];
}

extern "C" void kernel_launch(void* const* d_in, const int* in_sizes, int n_in,
                              void* d_out, int out_size, void* d_ws, size_t ws_size,
                              hipStream_t stream) {
  const float* fmap1  = (const float*)d_in[0];
  const float* fmap2  = (const float*)d_in[1];
  const float* coords = (const float*)d_in[2];
  float* out = (float*)d_out;
  _Float16* wsh = (_Float16*)d_ws;

  dim3 gA(P / 32, C / 32, 4), bA(32, 8);
  k_transpose_cl<<<gA, bA, 0, stream>>>(fmap1, fmap2, wsh);
  k_pyramid<<<2016, 256, 0, stream>>>(wsh);

  if (ws_size >= WS_NEEDED) {
    float* ot = (float*)((char*)d_ws + OT_OFF);
    k_sample<1><<<B2 * P, 256, 0, stream>>>(wsh, coords, ot);
    k_out_t<<<dim3(96, 32, 2), dim3(32, 8), 0, stream>>>(ot, out);
  } else {
    k_sample<0><<<B2 * P, 256, 0, stream>>>(wsh, coords, out);
  }
}

// Round 4
// 76.706 us; speedup vs baseline: 2.3394x; 1.2569x over previous
//
#include <hip/hip_runtime.h>

typedef _Float16 h2 __attribute__((ext_vector_type(2)));

// Problem constants (fixed by harness shapes)
static constexpr int B2   = 2;
static constexpr int C    = 256;
static constexpr int H    = 48;
static constexpr int W    = 64;
static constexpr int NLVL = 4;
static constexpr int D1   = 32;
static constexpr int P    = H * W;          // 3072
static constexpr int CHO  = NLVL * 8 * D1;  // 1024 output channels

// Workspace layout:
//   fp16 f1cl : [B][P][C]                  elems [0, F1E)
//   fp16 pyr  : levels 0..3 channels-last  elems [F1E, F1E+PYRE)
//   fp16 out_tmp : [B][P][CHO]             bytes [OT_OFF, ...)
static constexpr size_t F1E  = (size_t)B2 * P * C;
static constexpr size_t L0E  = 0;
static constexpr size_t L1E  = L0E + (size_t)B2 * 48 * 64 * C;
static constexpr size_t L2E  = L1E + (size_t)B2 * 24 * 32 * C;
static constexpr size_t L3E  = L2E + (size_t)B2 * 12 * 16 * C;
static constexpr size_t PYRE = L3E + (size_t)B2 * 6 * 8 * C;
static constexpr size_t OT_OFF    = 2 * (F1E + PYRE);   // bytes (8B aligned)
static constexpr size_t OT_BYTES  = (size_t)B2 * P * CHO * 2;
static constexpr size_t WS_NEEDED = OT_OFF + OT_BYTES;  // ~20 MB

__device__ __forceinline__ h2 u2h(unsigned u) {
  union { unsigned u; h2 h; } c; c.u = u; return c.h;
}
__device__ __forceinline__ unsigned h2u(h2 h) {
  union { unsigned u; h2 h; } c; c.h = h; return c.u;
}
__device__ __forceinline__ h2 habs2(h2 x) { return u2h(h2u(x) & 0x7FFF7FFFu); }

// ---------------------------------------------------------------------------
// A: fused prep. grid (4, 6, 32), block 256.
//   z <  16: fmap2 -> channels-last fp16 level0 AND pooled levels 1..3
//            (chained 2x2 means in LDS, matching the reference pyramid).
//   z >= 16: fmap1 -> channels-last fp16 (level0-style write only).
// Block covers a 16(x) x 8(y) pixel region for one 32-channel group.
// Threads (x16, y4, c4): each loads 16 f32 (4 rows x 64B per instr).
// ---------------------------------------------------------------------------
__global__ __launch_bounds__(256) void k_prep(
    const float* __restrict__ f1, const float* __restrict__ f2,
    _Float16* __restrict__ ws) {
  __shared__ float s0[32][8][16];  // [c][y][x] 16 KB
  __shared__ float s1[32][4][8];   // 4 KB
  __shared__ float s2[32][2][4];   // 1 KB
  const int x0 = blockIdx.x * 16;
  const int y0 = blockIdx.y * 8;
  const int z  = blockIdx.z;
  const bool isf1 = (z >= 16);
  const int zb = z & 15;
  const int b  = zb >> 3;
  const int c0 = (zb & 7) * 32;
  const int t  = threadIdx.x;
  const int tx = t & 15, ty = (t >> 4) & 3, tc = t >> 6;

  const float* src = (isf1 ? f1 : f2) + ((size_t)b * C + c0) * P;
#pragma unroll
  for (int k = 0; k < 8; ++k) {
    const int c = tc + 4 * k;
#pragma unroll
    for (int j = 0; j < 2; ++j) {
      const int y = ty + 4 * j;
      s0[c][y][tx] = src[(size_t)c * P + (size_t)(y0 + y) * W + (x0 + tx)];
    }
  }
  __syncthreads();

  // phase 2: write level0 (or f1cl); other threads compute level1 in LDS
  if (t < 128) {
    const int y = t >> 4, x = t & 15;
    union { uint4 q[4]; h2 hh[16]; } u;
#pragma unroll
    for (int e = 0; e < 16; ++e) {
      u.hh[e].x = (_Float16)s0[2 * e][y][x];
      u.hh[e].y = (_Float16)s0[2 * e + 1][y][x];
    }
    _Float16* dst = ws + (isf1 ? (size_t)0 : F1E + L0E) +
                    ((size_t)b * P + (size_t)(y0 + y) * W + (x0 + x)) * C + c0;
#pragma unroll
    for (int q = 0; q < 4; ++q) reinterpret_cast<uint4*>(dst)[q] = u.q[q];
  } else if (!isf1) {
    const int u0 = t - 128;
#pragma unroll
    for (int k = 0; k < 8; ++k) {
      const int idx = u0 + 128 * k;
      const int c = idx >> 5, r = idx & 31, y = r >> 3, x = r & 7;
      s1[c][y][x] = 0.25f * (s0[c][2 * y][2 * x] + s0[c][2 * y][2 * x + 1] +
                             s0[c][2 * y + 1][2 * x] + s0[c][2 * y + 1][2 * x + 1]);
    }
  }
  if (isf1) return;
  __syncthreads();

  // phase 3: write level1; compute level2 in LDS
  if (t < 32) {
    const int y = t >> 3, x = t & 7;
    union { uint4 q[4]; h2 hh[16]; } u;
#pragma unroll
    for (int e = 0; e < 16; ++e) {
      u.hh[e].x = (_Float16)s1[2 * e][y][x];
      u.hh[e].y = (_Float16)s1[2 * e + 1][y][x];
    }
    _Float16* dst = ws + F1E + L1E +
                    ((size_t)b * (24 * 32) + (size_t)(y0 / 2 + y) * 32 + (x0 / 2 + x)) * C + c0;
#pragma unroll
    for (int q = 0; q < 4; ++q) reinterpret_cast<uint4*>(dst)[q] = u.q[q];
  } else if (t >= 64 && t < 192) {
    const int u0 = t - 64;
#pragma unroll
    for (int k = 0; k < 2; ++k) {
      const int idx = u0 + 128 * k;
      const int c = idx >> 3, r = idx & 7, y = r >> 2, x = r & 3;
      s2[c][y][x] = 0.25f * (s1[c][2 * y][2 * x] + s1[c][2 * y][2 * x + 1] +
                             s1[c][2 * y + 1][2 * x] + s1[c][2 * y + 1][2 * x + 1]);
    }
  }
  __syncthreads();

  // phase 4: write level2; compute+write level3
  if (t < 8) {
    const int y = t >> 2, x = t & 3;
    union { uint4 q[4]; h2 hh[16]; } u;
#pragma unroll
    for (int e = 0; e < 16; ++e) {
      u.hh[e].x = (_Float16)s2[2 * e][y][x];
      u.hh[e].y = (_Float16)s2[2 * e + 1][y][x];
    }
    _Float16* dst = ws + F1E + L2E +
                    ((size_t)b * (12 * 16) + (size_t)(y0 / 4 + y) * 16 + (x0 / 4 + x)) * C + c0;
#pragma unroll
    for (int q = 0; q < 4; ++q) reinterpret_cast<uint4*>(dst)[q] = u.q[q];
  } else if (t >= 8 && t < 10) {
    const int x = t - 8;
    union { uint4 q[4]; h2 hh[16]; } u;
#pragma unroll
    for (int e = 0; e < 16; ++e) {
      const float a0 = 0.25f * (s2[2 * e][0][2 * x] + s2[2 * e][0][2 * x + 1] +
                                s2[2 * e][1][2 * x] + s2[2 * e][1][2 * x + 1]);
      const float a1 = 0.25f * (s2[2 * e + 1][0][2 * x] + s2[2 * e + 1][0][2 * x + 1] +
                                s2[2 * e + 1][1][2 * x] + s2[2 * e + 1][1][2 * x + 1]);
      u.hh[e].x = (_Float16)a0;
      u.hh[e].y = (_Float16)a1;
    }
    _Float16* dst = ws + F1E + L3E +
                    ((size_t)b * (6 * 8) + (size_t)(y0 / 8) * 8 + (x0 / 8 + x)) * C + c0;
#pragma unroll
    for (int q = 0; q < 4; ++q) reinterpret_cast<uint4*>(dst)[q] = u.q[q];
  }
}

// ---------------------------------------------------------------------------
// C: main sampler, software-pipelined (depth-1 corner-gather prefetch).
// One block per (b,pix), XCD-chunk-swizzled. 256 thr = 4 waves.
// ---------------------------------------------------------------------------
template <int STAGED>
__global__ __launch_bounds__(256) void k_sample(
    const _Float16* __restrict__ wsh, const float* __restrict__ coords,
    float* __restrict__ dstf, _Float16* __restrict__ dsth) {
  __shared__ uint4 s_off[128];
  __shared__ uint4 s_w[128];
  __shared__ float s_out[32 * 33];
  const int bid0 = blockIdx.x;
  const int bid  = (bid0 & 7) * 768 + (bid0 >> 3);  // XCD chunk swizzle
  const int b    = (bid >= P) ? 1 : 0;
  const int pix  = bid - b * P;
  const int t    = threadIdx.x;

  if (t < 128) {
    const int lvl = t >> 5, d = t & 31;
    const float cx = coords[(((size_t)(b * 2 + 0) * NLVL + lvl) * D1 + d) * P + pix];
    const float cy = coords[(((size_t)(b * 2 + 1) * NLVL + lvl) * D1 + d) * P + pix];
    const int Hi = H >> lvl, Wi = W >> lvl;
    const float sc = 1.0f / (float)(1 << lvl);
    const float xf = (cx + 0.5f) * sc - 0.5f;
    const float yf = (cy + 0.5f) * sc - 0.5f;
    const float x0f = floorf(xf), y0f = floorf(yf);
    const int x0 = (int)x0f, y0 = (int)y0f;
    const int x1 = x0 + 1, y1 = y0 + 1;
    const float fx = xf - x0f, fy = yf - y0f;
    const float vx0 = (x0 >= 0 && x0 < Wi) ? 1.f : 0.f;
    const float vx1 = (x1 >= 0 && x1 < Wi) ? 1.f : 0.f;
    const float vy0 = (y0 >= 0 && y0 < Hi) ? 1.f : 0.f;
    const float vy1 = (y1 >= 0 && y1 < Hi) ? 1.f : 0.f;
    const int x0c = min(max(x0, 0), Wi - 1), x1c = min(max(x1, 0), Wi - 1);
    const int y0c = min(max(y0, 0), Hi - 1), y1c = min(max(y1, 0), Hi - 1);
    h2 p00, p10, p01, p11;
    p00.x = p00.y = (_Float16)((1.f - fx) * (1.f - fy) * vx0 * vy0);
    p10.x = p10.y = (_Float16)(fx * (1.f - fy) * vx1 * vy0);
    p01.x = p01.y = (_Float16)((1.f - fx) * fy * vx0 * vy1);
    p11.x = p11.y = (_Float16)(fx * fy * vx1 * vy1);
    s_w[t] = make_uint4(h2u(p00), h2u(p10), h2u(p01), h2u(p11));
    s_off[t] = make_uint4((unsigned)(y0c * Wi + x0c) * (C * 2),
                          (unsigned)(y0c * Wi + x1c) * (C * 2),
                          (unsigned)(y1c * Wi + x0c) * (C * 2),
                          (unsigned)(y1c * Wi + x1c) * (C * 2));
  }

  const int lane = t & 63;
  const int wave = t >> 6;
  const int half = lane >> 5;
  const int lsub = lane & 31;
  const int head = lsub >> 2;
  const int chb  = lsub * 16;  // byte offset of this lane's 8 fp16 channels
  const int base_i = wave * 8 + half;

  // f1 fragment: 8 channels, packed fp16x2
  h2 f1h[4];
  {
    const uint4 v = *reinterpret_cast<const uint4*>(
        reinterpret_cast<const char*>(wsh + ((size_t)b * P + pix) * C) + chb);
    f1h[0] = u2h(v.x); f1h[1] = u2h(v.y); f1h[2] = u2h(v.z); f1h[3] = u2h(v.w);
  }
  const char* imgs[NLVL] = {
      reinterpret_cast<const char*>(wsh + F1E + L0E + (size_t)b * 48 * 64 * C),
      reinterpret_cast<const char*>(wsh + F1E + L1E + (size_t)b * 24 * 32 * C),
      reinterpret_cast<const char*>(wsh + F1E + L2E + (size_t)b * 12 * 16 * C),
      reinterpret_cast<const char*>(wsh + F1E + L3E + (size_t)b * 6 * 8 * C)};

  __syncthreads();

  // prologue: issue iteration-0 gathers
  uint4 v0, v1, v2, v3;
  {
    const uint4 o = s_off[base_i];
    const char* img = imgs[0];
    v0 = *reinterpret_cast<const uint4*>(img + o.x + chb);
    v1 = *reinterpret_cast<const uint4*>(img + o.y + chb);
    v2 = *reinterpret_cast<const uint4*>(img + o.z + chb);
    v3 = *reinterpret_cast<const uint4*>(img + o.w + chb);
  }

#pragma unroll
  for (int it = 0; it < 16; ++it) {
    const int lvl = it >> 2;
    const int d   = base_i + (it & 3) * 2;      // == wave*8 + i*2 + half
    const int idx = lvl * 32 + d;
    uint4 n0, n1, n2, n3;
    if (it < 15) {  // issue next iteration's gathers before computing
      const int nidx = ((it + 1) >> 2) * 32 + base_i + ((it + 1) & 3) * 2;
      const uint4 o = s_off[nidx];
      const char* img = imgs[(it + 1) >> 2];
      n0 = *reinterpret_cast<const uint4*>(img + o.x + chb);
      n1 = *reinterpret_cast<const uint4*>(img + o.y + chb);
      n2 = *reinterpret_cast<const uint4*>(img + o.z + chb);
      n3 = *reinterpret_cast<const uint4*>(img + o.w + chb);
    }
    const uint4 wq = s_w[idx];
    h2 a0 = {0, 0}, a1 = {0, 0}, a2 = {0, 0}, a3 = {0, 0};
    {
      const h2 w = u2h(wq.x);
      a0 += w * u2h(v0.x); a1 += w * u2h(v0.y); a2 += w * u2h(v0.z); a3 += w * u2h(v0.w);
    }
    {
      const h2 w = u2h(wq.y);
      a0 += w * u2h(v1.x); a1 += w * u2h(v1.y); a2 += w * u2h(v1.z); a3 += w * u2h(v1.w);
    }
    {
      const h2 w = u2h(wq.z);
      a0 += w * u2h(v2.x); a1 += w * u2h(v2.y); a2 += w * u2h(v2.z); a3 += w * u2h(v2.w);
    }
    {
      const h2 w = u2h(wq.w);
      a0 += w * u2h(v3.x); a1 += w * u2h(v3.y); a2 += w * u2h(v3.z); a3 += w * u2h(v3.w);
    }
    const h2 d0 = habs2(f1h[0] - a0);
    const h2 d1 = habs2(f1h[1] - a1);
    const h2 d2 = habs2(f1h[2] - a2);
    const h2 d3 = habs2(f1h[3] - a3);
    const h2 s  = (d0 + d1) + (d2 + d3);
    float a = (float)s.x + (float)s.y;
    a += __shfl_xor(a, 1);
    a += __shfl_xor(a, 2);
    if ((lane & 3) == 0) {
      if (STAGED) {
        s_out[d * 33 + lvl * 8 + head] = a * (1.0f / 32.0f);
      } else {
        const int ch_out = lvl * 256 + head * 32 + d;
        dstf[((size_t)b * CHO + ch_out) * P + pix] = a * (1.0f / 32.0f);
      }
    }
    if (it < 15) { v0 = n0; v1 = n1; v2 = n2; v3 = n3; }
  }

  if (STAGED) {
    __syncthreads();
    union { unsigned q[2]; h2 hh[2]; } u;
#pragma unroll
    for (int j = 0; j < 2; ++j) {
      const int ch0 = t * 4 + j * 2;
      const int ch1 = ch0 + 1;
      u.hh[j].x = (_Float16)s_out[(ch0 & 31) * 33 + (ch0 >> 8) * 8 + ((ch0 >> 5) & 7)];
      u.hh[j].y = (_Float16)s_out[(ch1 & 31) * 33 + (ch1 >> 8) * 8 + ((ch1 >> 5) & 7)];
    }
    *reinterpret_cast<uint2*>(dsth + ((size_t)b * P + pix) * CHO + t * 4) =
        make_uint2(u.q[0], u.q[1]);
  }
}

// ---------------------------------------------------------------------------
// D: transpose out_tmp fp16 [B][P][CHO] -> out f32 [B][CHO][P].
// grid (96, 32, 2), block (32,8)
// ---------------------------------------------------------------------------
__global__ __launch_bounds__(256) void k_out_t(
    const _Float16* __restrict__ ot, float* __restrict__ out) {
  __shared__ float tile[32][33];
  const int b  = blockIdx.z;
  const int p0 = blockIdx.x * 32;
  const int c0 = blockIdx.y * 32;
  const int tx = threadIdx.x, ty = threadIdx.y;
#pragma unroll
  for (int i = 0; i < 32; i += 8)
    tile[ty + i][tx] = (float)ot[((size_t)b * P + p0 + ty + i) * CHO + c0 + tx];
  __syncthreads();
#pragma unroll
  for (int i = 0; i < 32; i += 8)
    out[((size_t)b * CHO + c0 + ty + i) * P + p0 + tx] = tile[tx][ty + i];
}

extern "C" void kernel_launch(void* const* d_in, const int* in_sizes, int n_in,
                              void* d_out, int out_size, void* d_ws, size_t ws_size,
                              hipStream_t stream) {
  const float* fmap1  = (const float*)d_in[0];
  const float* fmap2  = (const float*)d_in[1];
  const float* coords = (const float*)d_in[2];
  float* out = (float*)d_out;
  _Float16* wsh = (_Float16*)d_ws;

  k_prep<<<dim3(4, 6, 32), 256, 0, stream>>>(fmap1, fmap2, wsh);

  if (ws_size >= WS_NEEDED) {
    _Float16* ot = (_Float16*)((char*)d_ws + OT_OFF);
    k_sample<1><<<B2 * P, 256, 0, stream>>>(wsh, coords, out, ot);
    k_out_t<<<dim3(96, 32, 2), dim3(32, 8), 0, stream>>>(ot, out);
  } else {
    k_sample<0><<<B2 * P, 256, 0, stream>>>(wsh, coords, out, nullptr);
  }
}